// Round 1
// baseline (673.835 us; speedup 1.0000x reference)
//
#include <hip/hip_runtime.h>
#include <hip/hip_bf16.h>
#include <stdint.h>

#define NN 50000     // nodes
#define NE 640000    // edges
#define NR 8         // relations
#define DIN 128
#define DHID 128
#define DOUT 64

__device__ __forceinline__ unsigned short f2bf(float f) {
    union { float f; unsigned u; } v; v.f = f;
    unsigned r = v.u + 0x7FFF + ((v.u >> 16) & 1);
    return (unsigned short)(r >> 16);
}
__device__ __forceinline__ float bf2f(unsigned short s) {
    union { unsigned u; float f; } v; v.u = ((unsigned)s) << 16; return v.f;
}

// ---------------- CSR build ----------------
__global__ void hist_kernel(const int* __restrict__ dst, int* __restrict__ counts) {
    int e = blockIdx.x * 256 + threadIdx.x;
    if (e < NE) atomicAdd(&counts[dst[e]], 1);
}

__global__ __launch_bounds__(1024) void scan_kernel(const int* __restrict__ counts,
                                                    int* __restrict__ offsets,
                                                    int* __restrict__ cursor, int n) {
    __shared__ int sm[1024];
    __shared__ int srun;
    int t = threadIdx.x;
    if (t == 0) srun = 0;
    __syncthreads();
    for (int base = 0; base < n; base += 1024) {
        int i = base + t;
        int v = (i < n) ? counts[i] : 0;
        sm[t] = v;
        __syncthreads();
        #pragma unroll
        for (int off = 1; off < 1024; off <<= 1) {
            int add = (t >= off) ? sm[t - off] : 0;
            __syncthreads();
            sm[t] += add;
            __syncthreads();
        }
        int run = srun;
        if (i < n) {
            int excl = run + sm[t] - v;
            offsets[i] = excl;
            cursor[i]  = excl;
        }
        __syncthreads();
        if (t == 1023) srun = run + sm[1023];
        __syncthreads();
    }
    if (t == 0) offsets[n] = srun;
}

__global__ void fill_kernel(const int* __restrict__ src, const int* __restrict__ dst,
                            const int* __restrict__ et, int* __restrict__ cursor,
                            int* __restrict__ rows) {
    int e = blockIdx.x * 256 + threadIdx.x;
    if (e < NE) {
        int pos = atomicAdd(&cursor[dst[e]], 1);
        rows[pos] = et[e] * NN + src[e];  // row into rel[r][node][:]
    }
}

// ---------------- GEMM: Out[r][m][nb+n] = sum_k A[m][k] * W[r][k][nb+n] ----------------
// Tile: 64(M) x 64(N), K=128 full. 256 threads, 4x4 micro-tile per thread.
// Xs fp32 padded (stride 132 words -> no 4-way bank conflict); Ws bf16 (16KB).
template<int NOUT, bool BF16OUT>
__global__ __launch_bounds__(256) void gemm_kernel(const float* __restrict__ A,
                                                   const float* __restrict__ W,
                                                   const float* __restrict__ bias,
                                                   void* __restrict__ Out, int M) {
    constexpr int K = 128;
    constexpr int MT = 64;
    constexpr int XS_STRIDE = K + 4;  // 132 words, multiple of 4 -> float4 ok
    __shared__ float Xs[MT * XS_STRIDE];          // 33792 B
    __shared__ unsigned short Wsb[K * 64];        // 16384 B

    const int t = threadIdx.x;
    const int r = blockIdx.z;
    const int m_base = blockIdx.x * MT;
    const int nb = blockIdx.y * 64;

    // stage W[r][:, nb:nb+64] -> bf16 LDS
    {
        const float* Wg = W + (size_t)r * K * NOUT;
        #pragma unroll
        for (int i = 0; i < 8; i++) {
            int f = t + i * 256;          // float4 id in [0,2048)
            int k = f >> 4;               // /16
            int c4 = (f & 15) << 2;
            float4 w = *(const float4*)(Wg + (size_t)k * NOUT + nb + c4);
            ushort4 wb;
            wb.x = f2bf(w.x); wb.y = f2bf(w.y); wb.z = f2bf(w.z); wb.w = f2bf(w.w);
            *(ushort4*)&Wsb[k * 64 + c4] = wb;
        }
    }
    // stage X tile fp32 -> padded LDS
    {
        #pragma unroll
        for (int i = 0; i < 8; i++) {
            int f = t + i * 256;          // float4 id in [0,2048)
            int ml = f >> 5;              // /32
            int k4 = (f & 31) << 2;
            float4 v = make_float4(0.f, 0.f, 0.f, 0.f);
            int m = m_base + ml;
            if (m < M) v = *(const float4*)(A + (size_t)m * K + k4);
            *(float4*)&Xs[ml * XS_STRIDE + k4] = v;
        }
    }
    __syncthreads();

    const int tx = t & 15;        // n-thread: cols 4*tx..4*tx+3
    const int ty = t >> 4;        // m-thread: rows 4*ty..4*ty+3
    float4 acc[4];
    #pragma unroll
    for (int i = 0; i < 4; i++) acc[i] = make_float4(0.f, 0.f, 0.f, 0.f);

    #pragma unroll 8
    for (int k = 0; k < K; k++) {
        ushort4 wv = *(const ushort4*)&Wsb[k * 64 + tx * 4];
        float w0 = bf2f(wv.x), w1 = bf2f(wv.y), w2 = bf2f(wv.z), w3 = bf2f(wv.w);
        #pragma unroll
        for (int i = 0; i < 4; i++) {
            float x = Xs[(ty * 4 + i) * XS_STRIDE + k];
            acc[i].x = fmaf(x, w0, acc[i].x);
            acc[i].y = fmaf(x, w1, acc[i].y);
            acc[i].z = fmaf(x, w2, acc[i].z);
            acc[i].w = fmaf(x, w3, acc[i].w);
        }
    }

    if (BF16OUT) {
        unsigned short* O = (unsigned short*)Out + (size_t)r * M * NOUT;
        #pragma unroll
        for (int i = 0; i < 4; i++) {
            int m = m_base + ty * 4 + i;
            if (m < M) {
                ushort4 pv;
                pv.x = f2bf(acc[i].x); pv.y = f2bf(acc[i].y);
                pv.z = f2bf(acc[i].z); pv.w = f2bf(acc[i].w);
                *(ushort4*)(O + (size_t)m * NOUT + nb + tx * 4) = pv;
            }
        }
    } else {
        float4 bv = make_float4(0.f, 0.f, 0.f, 0.f);
        if (bias) bv = *(const float4*)&bias[nb + tx * 4];
        float* O = (float*)Out;
        #pragma unroll
        for (int i = 0; i < 4; i++) {
            int m = m_base + ty * 4 + i;
            if (m < M) {
                float4 v = acc[i];
                v.x += bv.x; v.y += bv.y; v.z += bv.z; v.w += bv.w;
                *(float4*)(O + (size_t)m * NOUT + nb + tx * 4) = v;
            }
        }
    }
}

// ---------------- Per-node gather-sum (+ optional ReLU), io holds self+bias ----------------
template<int DIM, bool RELU>
__global__ __launch_bounds__(64) void gather_kernel(const int* __restrict__ offsets,
                                                    const int* __restrict__ rows,
                                                    const unsigned short* __restrict__ rel,
                                                    float* __restrict__ io) {
    int n = blockIdx.x;
    int t = threadIdx.x;
    int o0 = offsets[n], o1 = offsets[n + 1];
    if (DIM == 128) {
        float2 acc = *(const float2*)&io[(size_t)n * 128 + 2 * t];
        for (int j = o0; j < o1; j++) {
            size_t row = (size_t)rows[j];
            unsigned pv = *(const unsigned*)&rel[row * 128 + 2 * t];
            acc.x += bf2f((unsigned short)(pv & 0xffff));
            acc.y += bf2f((unsigned short)(pv >> 16));
        }
        if (RELU) { acc.x = fmaxf(acc.x, 0.f); acc.y = fmaxf(acc.y, 0.f); }
        *(float2*)&io[(size_t)n * 128 + 2 * t] = acc;
    } else {
        float acc = io[(size_t)n * 64 + t];
        for (int j = o0; j < o1; j++) {
            size_t row = (size_t)rows[j];
            acc += bf2f(rel[row * 64 + t]);
        }
        if (RELU) acc = fmaxf(acc, 0.f);
        io[(size_t)n * 64 + t] = acc;
    }
}

extern "C" void kernel_launch(void* const* d_in, const int* in_sizes, int n_in,
                              void* d_out, int out_size, void* d_ws, size_t ws_size,
                              hipStream_t stream) {
    const float* X   = (const float*)d_in[0];
    const int*   src = (const int*)d_in[1];
    const int*   dst = (const int*)d_in[2];
    const int*   et  = (const int*)d_in[3];
    const float* W1  = (const float*)d_in[4];
    const float* W1s = (const float*)d_in[5];
    const float* b1  = (const float*)d_in[6];
    const float* W2  = (const float*)d_in[7];
    const float* W2s = (const float*)d_in[8];
    const float* b2  = (const float*)d_in[9];
    float* out = (float*)d_out;

    // workspace carve (~131 MB)
    char* p = (char*)d_ws;
    unsigned short* rel = (unsigned short*)p; p += (size_t)NR * NN * DHID * 2;  // 102.4 MB (layer2 reuses)
    float* h    = (float*)p; p += (size_t)NN * DHID * 4;                        // 25.6 MB
    int* counts  = (int*)p; p += (size_t)NN * 4;
    int* offsets = (int*)p; p += (size_t)(NN + 4) * 4;
    int* cursor  = (int*)p; p += (size_t)NN * 4;
    int* rows    = (int*)p; p += (size_t)NE * 4;

    // CSR by dst (shared by both layers)
    hipMemsetAsync(counts, 0, NN * sizeof(int), stream);
    hist_kernel<<<(NE + 255) / 256, 256, 0, stream>>>(dst, counts);
    scan_kernel<<<1, 1024, 0, stream>>>(counts, offsets, cursor, NN);
    fill_kernel<<<(NE + 255) / 256, 256, 0, stream>>>(src, dst, et, cursor, rows);

    const int mblocks = (NN + 63) / 64;

    // Layer 1: rel1[r] = X @ W1[r]  (bf16 out);  h = X @ W1_self + b1 (fp32)
    dim3 gRel1(mblocks, DHID / 64, NR);
    gemm_kernel<DHID, true><<<gRel1, 256, 0, stream>>>(X, W1, nullptr, rel, NN);
    dim3 gSelf1(mblocks, DHID / 64, 1);
    gemm_kernel<DHID, false><<<gSelf1, 256, 0, stream>>>(X, W1s, b1, h, NN);
    gather_kernel<DHID, true><<<NN, 64, 0, stream>>>(offsets, rows, rel, h);

    // Layer 2: rel2[r] = h @ W2[r] (bf16, reuse rel buf); out = h @ W2_self + b2; gather
    dim3 gRel2(mblocks, DOUT / 64, NR);
    gemm_kernel<DOUT, true><<<gRel2, 256, 0, stream>>>(h, W2, nullptr, rel, NN);
    dim3 gSelf2(mblocks, DOUT / 64, 1);
    gemm_kernel<DOUT, false><<<gSelf2, 256, 0, stream>>>(h, W2s, b2, out, NN);
    gather_kernel<DOUT, false><<<NN, 64, 0, stream>>>(offsets, rows, rel, out);
}

// Round 2
// 431.454 us; speedup vs baseline: 1.5618x; 1.5618x over previous
//
#include <hip/hip_runtime.h>
#include <hip/hip_bf16.h>
#include <stdint.h>

#define NN 50000     // nodes
#define NE 640000    // edges
#define NR 8         // relations

typedef short bf16x8 __attribute__((ext_vector_type(8)));
typedef float f32x4  __attribute__((ext_vector_type(4)));

__device__ __forceinline__ unsigned short f2bf(float f) {
    union { float f; unsigned u; } v; v.f = f;
    unsigned r = v.u + 0x7FFF + ((v.u >> 16) & 1);
    return (unsigned short)(r >> 16);
}
__device__ __forceinline__ float bf2f(unsigned short s) {
    union { unsigned u; float f; } v; v.u = ((unsigned)s) << 16; return v.f;
}

// ---------------- CSR build ----------------
__global__ void hist_kernel(const int* __restrict__ dst, int* __restrict__ counts) {
    int e = blockIdx.x * 256 + threadIdx.x;
    if (e < NE) atomicAdd(&counts[dst[e]], 1);
}

__global__ __launch_bounds__(1024) void scan_kernel(const int* __restrict__ counts,
                                                    int* __restrict__ offsets,
                                                    int* __restrict__ cursor, int n) {
    __shared__ int sm[1024];
    __shared__ int srun;
    int t = threadIdx.x;
    if (t == 0) srun = 0;
    __syncthreads();
    for (int base = 0; base < n; base += 1024) {
        int i = base + t;
        int v = (i < n) ? counts[i] : 0;
        sm[t] = v;
        __syncthreads();
        #pragma unroll
        for (int off = 1; off < 1024; off <<= 1) {
            int add = (t >= off) ? sm[t - off] : 0;
            __syncthreads();
            sm[t] += add;
            __syncthreads();
        }
        int run = srun;
        if (i < n) {
            int excl = run + sm[t] - v;
            offsets[i] = excl;
            cursor[i]  = excl;
        }
        __syncthreads();
        if (t == 1023) srun = run + sm[1023];
        __syncthreads();
    }
    if (t == 0) offsets[n] = srun;
}

__global__ void fill_kernel(const int* __restrict__ src, const int* __restrict__ dst,
                            const int* __restrict__ et, int* __restrict__ cursor,
                            int* __restrict__ rows) {
    int e = blockIdx.x * 256 + threadIdx.x;
    if (e < NE) {
        int pos = atomicAdd(&cursor[dst[e]], 1);
        rows[pos] = et[e] * NN + src[e];  // row into rel[r][node][:]
    }
}

// ---------------- dtype prep ----------------
// fp32 -> bf16, 8 elems/thread
__global__ void cvt_bf16_kernel(const float* __restrict__ in, unsigned short* __restrict__ outp,
                                int n8) {
    int i = blockIdx.x * 256 + threadIdx.x;
    if (i >= n8) return;
    const float4* pp = (const float4*)in + (size_t)i * 2;
    float4 a = pp[0], b = pp[1];
    uint4 o;
    o.x = (unsigned)f2bf(a.x) | ((unsigned)f2bf(a.y) << 16);
    o.y = (unsigned)f2bf(a.z) | ((unsigned)f2bf(a.w) << 16);
    o.z = (unsigned)f2bf(b.x) | ((unsigned)f2bf(b.y) << 16);
    o.w = (unsigned)f2bf(b.z) | ((unsigned)f2bf(b.w) << 16);
    ((uint4*)outp)[i] = o;
}

// Build WT[c][k] bf16, c in [0, 9*DOUTV): c = r*DOUTV+o -> W[r][k][o]; c >= 8*DOUTV -> Wself[k][o]
template<int DOUTV>
__global__ void prepW_kernel(const float* __restrict__ W, const float* __restrict__ Wself,
                             unsigned short* __restrict__ WT) {
    int idx = blockIdx.x * 256 + threadIdx.x;
    if (idx >= 9 * DOUTV * 128) return;
    int k = idx & 127;
    int c = idx >> 7;
    int r = c / DOUTV;                 // DOUTV pow2 -> shift
    int o = c - r * DOUTV;
    float v = (r < 8) ? W[((size_t)r * 128 + k) * DOUTV + o]
                      : Wself[(size_t)k * DOUTV + o];
    WT[idx] = f2bf(v);
}

// ---------------- MFMA GEMM ----------------
// C[m][n] = sum_k A[m][k] * WT[n][k], K=128 (one LDS stage, one barrier).
// Block tile BM x BN, 256 threads = 4 waves, each wave 64x64 (4x4 frags of 16x16x32).
// LDS layout: row-major rows of 256B (128 bf16), 16B chunk c stored at c ^ (row&15)
// -> fragment ds_read_b128 is 2-way bank aliased (free, m136).
// gridDim.y = 9: y<8 -> relation y (bf16 out), y==8 -> self-loop (fp32 out + bias).
template<int BN, int BM>
__global__ __launch_bounds__(256) void mfma_gemm_kernel(
        const unsigned short* __restrict__ A,     // [M][128] bf16
        const unsigned short* __restrict__ WT,    // [9*BN][128] bf16 (row = out col)
        const float*  __restrict__ bias,          // [BN] (self block)
        unsigned short* __restrict__ relout,      // [NR][M][BN] bf16
        float*  __restrict__ selfout,             // [M][BN] fp32
        int M) {
    __shared__ unsigned short Xs[BM * 128];
    __shared__ unsigned short Ws[BN * 128];
    const int t  = threadIdx.x;
    const int mb = blockIdx.x;
    const int bn = blockIdx.y;   // 0..8

    // stage A tile (guard tail rows with zeros)
    #pragma unroll
    for (int i = 0; i < BM / 16; i++) {
        int g = t + i * 256;             // 16B chunk id
        int row = g >> 4, c = g & 15;
        int m = mb * BM + row;
        float4 v = make_float4(0.f, 0.f, 0.f, 0.f);
        if (m < M) v = *(const float4*)(A + (size_t)m * 128 + c * 8);
        *(float4*)((char*)Xs + row * 256 + ((c ^ (row & 15)) << 4)) = v;
    }
    // stage B tile (rows bn*BN .. bn*BN+BN-1 of WT, always in range)
    #pragma unroll
    for (int i = 0; i < BN / 16; i++) {
        int g = t + i * 256;
        int row = g >> 4, c = g & 15;
        float4 v = *(const float4*)(WT + ((size_t)bn * BN + row) * 128 + c * 8);
        *(float4*)((char*)Ws + row * 256 + ((c ^ (row & 15)) << 4)) = v;
    }
    __syncthreads();

    const int lane = t & 63;
    const int w    = t >> 6;
    const int wm   = (BN == 128) ? (w & 1) * 64 : w * 64;
    const int wn   = (BN == 128) ? (w >> 1) * 64 : 0;
    const int r15  = lane & 15;
    const int q    = lane >> 4;

    f32x4 acc[4][4] = {};
    #pragma unroll
    for (int ks = 0; ks < 4; ks++) {
        bf16x8 af[4], bfr[4];
        int c = (ks * 4 + q) ^ r15;      // swizzled chunk (row&15 == r15 for all frag rows)
        #pragma unroll
        for (int i = 0; i < 4; i++) {
            int row = wm + i * 16 + r15;
            af[i] = *(const bf16x8*)((const char*)Xs + row * 256 + (c << 4));
        }
        #pragma unroll
        for (int j = 0; j < 4; j++) {
            int row = wn + j * 16 + r15;
            bfr[j] = *(const bf16x8*)((const char*)Ws + row * 256 + (c << 4));
        }
        #pragma unroll
        for (int i = 0; i < 4; i++)
            #pragma unroll
            for (int j = 0; j < 4; j++)
                acc[i][j] = __builtin_amdgcn_mfma_f32_16x16x32_bf16(af[i], bfr[j], acc[i][j], 0, 0, 0);
    }

    // epilogue: C/D layout col=lane&15, row=(lane>>4)*4+reg (m89-verified)
    const int rowq = q * 4;
    if (bn < 8) {
        unsigned short* O = relout + (size_t)bn * M * BN;
        #pragma unroll
        for (int i = 0; i < 4; i++) {
            #pragma unroll
            for (int reg = 0; reg < 4; reg++) {
                int m = mb * BM + wm + i * 16 + rowq + reg;
                if (m < M) {
                    #pragma unroll
                    for (int j = 0; j < 4; j++) {
                        int n = wn + j * 16 + r15;
                        O[(size_t)m * BN + n] = f2bf(acc[i][j][reg]);
                    }
                }
            }
        }
    } else {
        #pragma unroll
        for (int j = 0; j < 4; j++) {
            float bv = bias[wn + j * 16 + r15];
            #pragma unroll
            for (int i = 0; i < 4; i++) {
                #pragma unroll
                for (int reg = 0; reg < 4; reg++) {
                    int m = mb * BM + wm + i * 16 + rowq + reg;
                    if (m < M)
                        selfout[(size_t)m * BN + wn + j * 16 + r15] = acc[i][j][reg] + bv;
                }
            }
        }
    }
}

// ---------------- Per-node gather-sum ----------------
template<int DIM, bool RELU, bool OUTBF16>
__global__ __launch_bounds__(64) void gather_kernel(
        const int* __restrict__ offsets, const int* __restrict__ rows,
        const unsigned short* __restrict__ rel, const float* __restrict__ selfin,
        void* __restrict__ outp) {
    int n = blockIdx.x;
    int t = threadIdx.x;
    int o0 = offsets[n], o1 = offsets[n + 1];
    if (DIM == 128) {
        float2 acc = *(const float2*)&selfin[(size_t)n * 128 + 2 * t];
        for (int j = o0; j < o1; j++) {
            size_t row = (size_t)rows[j];
            unsigned pv = *(const unsigned*)&rel[row * 128 + 2 * t];
            acc.x += bf2f((unsigned short)(pv & 0xffff));
            acc.y += bf2f((unsigned short)(pv >> 16));
        }
        if (RELU) { acc.x = fmaxf(acc.x, 0.f); acc.y = fmaxf(acc.y, 0.f); }
        if (OUTBF16) {
            unsigned pv = (unsigned)f2bf(acc.x) | ((unsigned)f2bf(acc.y) << 16);
            ((unsigned*)outp)[(size_t)n * 64 + t] = pv;
        } else {
            ((float2*)outp)[(size_t)n * 64 + t] = acc;
        }
    } else {
        float acc = selfin[(size_t)n * 64 + t];
        for (int j = o0; j < o1; j++)
            acc += bf2f(rel[(size_t)rows[j] * 64 + t]);
        if (RELU) acc = fmaxf(acc, 0.f);
        ((float*)outp)[(size_t)n * 64 + t] = acc;
    }
}

extern "C" void kernel_launch(void* const* d_in, const int* in_sizes, int n_in,
                              void* d_out, int out_size, void* d_ws, size_t ws_size,
                              hipStream_t stream) {
    const float* X   = (const float*)d_in[0];
    const int*   src = (const int*)d_in[1];
    const int*   dst = (const int*)d_in[2];
    const int*   et  = (const int*)d_in[3];
    const float* W1  = (const float*)d_in[4];
    const float* W1s = (const float*)d_in[5];
    const float* b1  = (const float*)d_in[6];
    const float* W2  = (const float*)d_in[7];
    const float* W2s = (const float*)d_in[8];
    const float* b2  = (const float*)d_in[9];
    float* out = (float*)d_out;

    // workspace carve (~144 MB)
    char* p = (char*)d_ws;
    unsigned short* rel = (unsigned short*)p; p += (size_t)NR * NN * 128 * 2;  // 102.4 MB (layer2 reuses)
    float* hself = (float*)p;          p += (size_t)NN * 128 * 4;              // 25.6 MB
    unsigned short* Xbf = (unsigned short*)p; p += (size_t)NN * 128 * 2;       // 12.8 MB (reused as hbf)
    unsigned short* W1T = (unsigned short*)p; p += (size_t)9 * 128 * 128 * 2;  // 288 KB
    unsigned short* W2T = (unsigned short*)p; p += (size_t)9 * 64 * 128 * 2;   // 144 KB
    int* counts  = (int*)p; p += (size_t)NN * 4;
    int* offsets = (int*)p; p += (size_t)(NN + 4) * 4;
    int* cursor  = (int*)p; p += (size_t)NN * 4;
    int* rows    = (int*)p; p += (size_t)NE * 4;

    // CSR by dst (shared by both layers)
    hipMemsetAsync(counts, 0, NN * sizeof(int), stream);
    hist_kernel<<<(NE + 255) / 256, 256, 0, stream>>>(dst, counts);
    scan_kernel<<<1, 1024, 0, stream>>>(counts, offsets, cursor, NN);
    fill_kernel<<<(NE + 255) / 256, 256, 0, stream>>>(src, dst, et, cursor, rows);

    // dtype prep
    cvt_bf16_kernel<<<(NN * 128 / 8 + 255) / 256, 256, 0, stream>>>(X, Xbf, NN * 128 / 8);
    prepW_kernel<128><<<(9 * 128 * 128 + 255) / 256, 256, 0, stream>>>(W1, W1s, W1T);
    prepW_kernel<64><<<(9 * 64 * 128 + 255) / 256, 256, 0, stream>>>(W2, W2s, W2T);

    // Layer 1 fused GEMM: rel1[r] = Xbf @ W1[r] (bf16), hself = Xbf @ W1s + b1 (fp32)
    mfma_gemm_kernel<128, 128><<<dim3((NN + 127) / 128, 9), 256, 0, stream>>>(
        Xbf, W1T, b1, rel, hself, NN);
    // h (bf16, overlaid on Xbf) = relu(agg + hself)
    gather_kernel<128, true, true><<<NN, 64, 0, stream>>>(offsets, rows, rel, hself, Xbf);

    // Layer 2 fused GEMM: rel2[r] = h @ W2[r] (bf16, reuse rel), out = h @ W2s + b2 (fp32)
    mfma_gemm_kernel<64, 256><<<dim3((NN + 255) / 256, 9), 256, 0, stream>>>(
        Xbf, W2T, b2, rel, out, NN);
    gather_kernel<64, false, false><<<NN, 64, 0, stream>>>(offsets, rows, rel, out, out);
}

// Round 3
// 347.527 us; speedup vs baseline: 1.9389x; 1.2415x over previous
//
#include <hip/hip_runtime.h>
#include <hip/hip_bf16.h>
#include <stdint.h>

#define NN 50000     // nodes
#define NE 640000    // edges
#define NR 8         // relations
#define NB_SCAN ((NN + 1023) / 1024)   // 49 scan blocks

typedef short bf16x8 __attribute__((ext_vector_type(8)));
typedef float f32x4  __attribute__((ext_vector_type(4)));

__device__ __forceinline__ unsigned short f2bf(float f) {
    union { float f; unsigned u; } v; v.f = f;
    unsigned r = v.u + 0x7FFF + ((v.u >> 16) & 1);
    return (unsigned short)(r >> 16);
}
__device__ __forceinline__ float bf2f(unsigned short s) {
    union { unsigned u; float f; } v; v.u = ((unsigned)s) << 16; return v.f;
}

// ---------------- CSR build ----------------
__global__ void hist_kernel(const int* __restrict__ dst, int* __restrict__ counts) {
    int e = blockIdx.x * 256 + threadIdx.x;
    if (e < NE) atomicAdd(&counts[dst[e]], 1);
}

// K1: per-block reduce of counts -> bsum[block]
__global__ __launch_bounds__(1024) void blocksum_kernel(const int* __restrict__ counts,
                                                        int* __restrict__ bsum) {
    __shared__ int ws[16];
    int i = blockIdx.x * 1024 + threadIdx.x;
    int v = (i < NN) ? counts[i] : 0;
    #pragma unroll
    for (int d = 32; d > 0; d >>= 1) v += __shfl_down(v, d, 64);
    int wid = threadIdx.x >> 6, lane = threadIdx.x & 63;
    if (lane == 0) ws[wid] = v;
    __syncthreads();
    if (threadIdx.x < 16) {
        int s = ws[threadIdx.x];
        #pragma unroll
        for (int d = 8; d > 0; d >>= 1) s += __shfl_down(s, d, 16);
        if (threadIdx.x == 0) bsum[blockIdx.x] = s;
    }
}

// K2: one wave scans the 49 block sums -> exclusive bases; writes total to offsets[NN]
__global__ __launch_bounds__(64) void scanbase_kernel(const int* __restrict__ bsum,
                                                      int* __restrict__ base,
                                                      int* __restrict__ offsets) {
    int lane = threadIdx.x;
    int v = (lane < NB_SCAN) ? bsum[lane] : 0;
    int incl = v;
    #pragma unroll
    for (int d = 1; d < 64; d <<= 1) {
        int n = __shfl_up(incl, d, 64);
        if (lane >= d) incl += n;
    }
    if (lane < NB_SCAN) base[lane] = incl - v;
    if (lane == 63) offsets[NN] = incl;   // grand total (lanes past NB_SCAN add 0)
}

// K3: local scan + base add -> offsets & cursor
__global__ __launch_bounds__(1024) void scanlocal_kernel(const int* __restrict__ counts,
                                                         const int* __restrict__ base,
                                                         int* __restrict__ offsets,
                                                         int* __restrict__ cursor) {
    __shared__ int ws[16];
    __shared__ int wbase[16];
    int t = threadIdx.x;
    int i = blockIdx.x * 1024 + t;
    int v = (i < NN) ? counts[i] : 0;
    int lane = t & 63, wid = t >> 6;
    int incl = v;
    #pragma unroll
    for (int d = 1; d < 64; d <<= 1) {
        int n = __shfl_up(incl, d, 64);
        if (lane >= d) incl += n;
    }
    if (lane == 63) ws[wid] = incl;
    __syncthreads();
    if (t < 16) {
        int s = ws[t];
        int si = s;
        #pragma unroll
        for (int d = 1; d < 16; d <<= 1) {
            int n = __shfl_up(si, d, 16);
            if (t >= d) si += n;
        }
        wbase[t] = si - s;
    }
    __syncthreads();
    if (i < NN) {
        int excl = base[blockIdx.x] + wbase[wid] + incl - v;
        offsets[i] = excl;
        cursor[i]  = excl;
    }
}

__global__ void fill_kernel(const int* __restrict__ src, const int* __restrict__ dst,
                            const int* __restrict__ et, int* __restrict__ cursor,
                            int* __restrict__ rows) {
    int e = blockIdx.x * 256 + threadIdx.x;
    if (e < NE) {
        int pos = atomicAdd(&cursor[dst[e]], 1);
        rows[pos] = et[e] * NN + src[e];  // row into rel[r][node][:]
    }
}

// ---------------- dtype prep ----------------
__global__ void cvt_bf16_kernel(const float* __restrict__ in, unsigned short* __restrict__ outp,
                                int n8) {
    int i = blockIdx.x * 256 + threadIdx.x;
    if (i >= n8) return;
    const float4* pp = (const float4*)in + (size_t)i * 2;
    float4 a = pp[0], b = pp[1];
    uint4 o;
    o.x = (unsigned)f2bf(a.x) | ((unsigned)f2bf(a.y) << 16);
    o.y = (unsigned)f2bf(a.z) | ((unsigned)f2bf(a.w) << 16);
    o.z = (unsigned)f2bf(b.x) | ((unsigned)f2bf(b.y) << 16);
    o.w = (unsigned)f2bf(b.z) | ((unsigned)f2bf(b.w) << 16);
    ((uint4*)outp)[i] = o;
}

// Build WT[c][k] bf16, c = r*DOUTV+o -> W[r][k][o]; r==8 -> Wself[k][o]
template<int DOUTV>
__global__ void prepW_kernel(const float* __restrict__ W, const float* __restrict__ Wself,
                             unsigned short* __restrict__ WT) {
    int idx = blockIdx.x * 256 + threadIdx.x;
    if (idx >= 9 * DOUTV * 128) return;
    int k = idx & 127;
    int c = idx >> 7;
    int r = c / DOUTV;
    int o = c - r * DOUTV;
    float v = (r < 8) ? W[((size_t)r * 128 + k) * DOUTV + o]
                      : Wself[(size_t)k * DOUTV + o];
    WT[idx] = f2bf(v);
}

// ---------------- MFMA GEMM ----------------
// C[m][n] = sum_k A[m][k] * WT[n][k], K=128 (one LDS stage, one barrier).
// Block tile BM x BN, 256 threads = 4 waves, each wave 64x64 (4x4 frags of 16x16x32).
// LDS: rows of 256B, 16B chunk c stored at c ^ (row&15) -> frag reads 2-way aliased (free).
// gridDim.y = 9: y<8 -> relation y (bf16 out), y==8 -> self-loop (fp32 out + bias).
template<int BN, int BM>
__global__ __launch_bounds__(256) void mfma_gemm_kernel(
        const unsigned short* __restrict__ A,     // [M][128] bf16
        const unsigned short* __restrict__ WT,    // [9*BN][128] bf16 (row = out col)
        const float*  __restrict__ bias,          // [BN] (self block)
        unsigned short* __restrict__ relout,      // [NR][M][BN] bf16
        float*  __restrict__ selfout,             // [M][BN] fp32
        int M) {
    __shared__ unsigned short Xs[BM * 128];
    __shared__ unsigned short Ws[BN * 128];
    const int t  = threadIdx.x;
    const int mb = blockIdx.x;
    const int bn = blockIdx.y;   // 0..8

    #pragma unroll
    for (int i = 0; i < BM / 16; i++) {
        int g = t + i * 256;             // 16B chunk id
        int row = g >> 4, c = g & 15;
        int m = mb * BM + row;
        float4 v = make_float4(0.f, 0.f, 0.f, 0.f);
        if (m < M) v = *(const float4*)(A + (size_t)m * 128 + c * 8);
        *(float4*)((char*)Xs + row * 256 + ((c ^ (row & 15)) << 4)) = v;
    }
    #pragma unroll
    for (int i = 0; i < BN / 16; i++) {
        int g = t + i * 256;
        int row = g >> 4, c = g & 15;
        float4 v = *(const float4*)(WT + ((size_t)bn * BN + row) * 128 + c * 8);
        *(float4*)((char*)Ws + row * 256 + ((c ^ (row & 15)) << 4)) = v;
    }
    __syncthreads();

    const int lane = t & 63;
    const int w    = t >> 6;
    const int wm   = (BN == 128) ? (w & 1) * 64 : w * 64;
    const int wn   = (BN == 128) ? (w >> 1) * 64 : 0;
    const int r15  = lane & 15;
    const int q    = lane >> 4;

    f32x4 acc[4][4] = {};
    #pragma unroll
    for (int ks = 0; ks < 4; ks++) {
        bf16x8 af[4], bfr[4];
        int c = (ks * 4 + q) ^ r15;
        #pragma unroll
        for (int i = 0; i < 4; i++) {
            int row = wm + i * 16 + r15;
            af[i] = *(const bf16x8*)((const char*)Xs + row * 256 + (c << 4));
        }
        #pragma unroll
        for (int j = 0; j < 4; j++) {
            int row = wn + j * 16 + r15;
            bfr[j] = *(const bf16x8*)((const char*)Ws + row * 256 + (c << 4));
        }
        #pragma unroll
        for (int i = 0; i < 4; i++)
            #pragma unroll
            for (int j = 0; j < 4; j++)
                acc[i][j] = __builtin_amdgcn_mfma_f32_16x16x32_bf16(af[i], bfr[j], acc[i][j], 0, 0, 0);
    }

    const int rowq = q * 4;
    if (bn < 8) {
        unsigned short* O = relout + (size_t)bn * M * BN;
        #pragma unroll
        for (int i = 0; i < 4; i++) {
            #pragma unroll
            for (int reg = 0; reg < 4; reg++) {
                int m = mb * BM + wm + i * 16 + rowq + reg;
                if (m < M) {
                    #pragma unroll
                    for (int j = 0; j < 4; j++) {
                        int n = wn + j * 16 + r15;
                        O[(size_t)m * BN + n] = f2bf(acc[i][j][reg]);
                    }
                }
            }
        }
    } else {
        #pragma unroll
        for (int j = 0; j < 4; j++) {
            float bv = bias[wn + j * 16 + r15];
            #pragma unroll
            for (int i = 0; i < 4; i++) {
                #pragma unroll
                for (int reg = 0; reg < 4; reg++) {
                    int m = mb * BM + wm + i * 16 + rowq + reg;
                    if (m < M)
                        selfout[(size_t)m * BN + wn + j * 16 + r15] = acc[i][j][reg] + bv;
                }
            }
        }
    }
}

// ---------------- Per-node gather-sum ----------------
template<int DIM, bool RELU, bool OUTBF16>
__global__ __launch_bounds__(64) void gather_kernel(
        const int* __restrict__ offsets, const int* __restrict__ rows,
        const unsigned short* __restrict__ rel, const float* __restrict__ selfin,
        void* __restrict__ outp) {
    int n = blockIdx.x;
    int t = threadIdx.x;
    int o0 = offsets[n], o1 = offsets[n + 1];
    if (DIM == 128) {
        float2 acc = *(const float2*)&selfin[(size_t)n * 128 + 2 * t];
        for (int j = o0; j < o1; j++) {
            size_t row = (size_t)rows[j];
            unsigned pv = *(const unsigned*)&rel[row * 128 + 2 * t];
            acc.x += bf2f((unsigned short)(pv & 0xffff));
            acc.y += bf2f((unsigned short)(pv >> 16));
        }
        if (RELU) { acc.x = fmaxf(acc.x, 0.f); acc.y = fmaxf(acc.y, 0.f); }
        if (OUTBF16) {
            unsigned pv = (unsigned)f2bf(acc.x) | ((unsigned)f2bf(acc.y) << 16);
            ((unsigned*)outp)[(size_t)n * 64 + t] = pv;
        } else {
            ((float2*)outp)[(size_t)n * 64 + t] = acc;
        }
    } else {
        float acc = selfin[(size_t)n * 64 + t];
        for (int j = o0; j < o1; j++)
            acc += bf2f(rel[(size_t)rows[j] * 64 + t]);
        if (RELU) acc = fmaxf(acc, 0.f);
        ((float*)outp)[(size_t)n * 64 + t] = acc;
    }
}

extern "C" void kernel_launch(void* const* d_in, const int* in_sizes, int n_in,
                              void* d_out, int out_size, void* d_ws, size_t ws_size,
                              hipStream_t stream) {
    const float* X   = (const float*)d_in[0];
    const int*   src = (const int*)d_in[1];
    const int*   dst = (const int*)d_in[2];
    const int*   et  = (const int*)d_in[3];
    const float* W1  = (const float*)d_in[4];
    const float* W1s = (const float*)d_in[5];
    const float* b1  = (const float*)d_in[6];
    const float* W2  = (const float*)d_in[7];
    const float* W2s = (const float*)d_in[8];
    const float* b2  = (const float*)d_in[9];
    float* out = (float*)d_out;

    // workspace carve (~144 MB)
    char* p = (char*)d_ws;
    unsigned short* rel = (unsigned short*)p; p += (size_t)NR * NN * 128 * 2;  // 102.4 MB (layer2 reuses)
    float* hself = (float*)p;          p += (size_t)NN * 128 * 4;              // 25.6 MB
    unsigned short* Xbf = (unsigned short*)p; p += (size_t)NN * 128 * 2;       // 12.8 MB (reused as hbf)
    unsigned short* W1T = (unsigned short*)p; p += (size_t)9 * 128 * 128 * 2;  // 288 KB
    unsigned short* W2T = (unsigned short*)p; p += (size_t)9 * 64 * 128 * 2;   // 144 KB
    int* counts  = (int*)p; p += (size_t)NN * 4;
    int* offsets = (int*)p; p += (size_t)(NN + 4) * 4;
    int* cursor  = (int*)p; p += (size_t)NN * 4;
    int* rows    = (int*)p; p += (size_t)NE * 4;
    int* bsum    = (int*)p; p += 64 * 4;
    int* bbase   = (int*)p; p += 64 * 4;

    // CSR by dst (shared by both layers) — multi-block scan
    hipMemsetAsync(counts, 0, NN * sizeof(int), stream);
    hist_kernel<<<(NE + 255) / 256, 256, 0, stream>>>(dst, counts);
    blocksum_kernel<<<NB_SCAN, 1024, 0, stream>>>(counts, bsum);
    scanbase_kernel<<<1, 64, 0, stream>>>(bsum, bbase, offsets);
    scanlocal_kernel<<<NB_SCAN, 1024, 0, stream>>>(counts, bbase, offsets, cursor);
    fill_kernel<<<(NE + 255) / 256, 256, 0, stream>>>(src, dst, et, cursor, rows);

    // dtype prep
    cvt_bf16_kernel<<<(NN * 128 / 8 + 255) / 256, 256, 0, stream>>>(X, Xbf, NN * 128 / 8);
    prepW_kernel<128><<<(9 * 128 * 128 + 255) / 256, 256, 0, stream>>>(W1, W1s, W1T);
    prepW_kernel<64><<<(9 * 64 * 128 + 255) / 256, 256, 0, stream>>>(W2, W2s, W2T);

    // Layer 1 fused GEMM: rel1[r] = Xbf @ W1[r] (bf16), hself = Xbf @ W1s + b1 (fp32)
    mfma_gemm_kernel<128, 128><<<dim3((NN + 127) / 128, 9), 256, 0, stream>>>(
        Xbf, W1T, b1, rel, hself, NN);
    gather_kernel<128, true, true><<<NN, 64, 0, stream>>>(offsets, rows, rel, hself, Xbf);

    // Layer 2 fused GEMM: rel2[r] = h @ W2[r] (bf16, reuse rel), out = h @ W2s + b2 (fp32)
    mfma_gemm_kernel<64, 256><<<dim3((NN + 255) / 256, 9), 256, 0, stream>>>(
        Xbf, W2T, b2, rel, out, NN);
    gather_kernel<64, false, false><<<NN, 64, 0, stream>>>(offsets, rows, rel, out, out);
}